// Round 6
// baseline (1507.646 us; speedup 1.0000x reference)
//
#include <hip/hip_runtime.h>
#include <cstdint>
#include <cstddef>

#define B_ 2048
#define N_ 62
#define FIN_ 128
#define HID_ 512
#define HEADS_ 8
#define FOUT_ 64
#define LAYERS_ 3
#define M_ (B_*N_)           // 126976
#define CHG_ 256             // graphs per chunk: hTg = 256*8*4096 u16 = 16.78MB
                             // MUST fit in xb alias (16.25M u16 = 32.5MB). OK.
#define L2E 1.44269504f

typedef __bf16 bf16x8 __attribute__((ext_vector_type(8)));
typedef float  f32x4  __attribute__((ext_vector_type(4)));
typedef unsigned short u16;

static __device__ __forceinline__ u16 f2bf(float f) {
    union { float f; uint32_t u; } v; v.f = f;
    uint32_t u = v.u;
    return (u16)((u + 0x7fffu + ((u >> 16) & 1u)) >> 16);
}
static __device__ __forceinline__ float bf2f(u16 s) {
    union { uint32_t u; float f; } v; v.u = ((uint32_t)s) << 16;
    return v.f;
}

// ---------------------------------------------------------------------------
// xb = BN(x) cast to bf16
// ---------------------------------------------------------------------------
__global__ __launch_bounds__(256) void bn_cast(
    const float* __restrict__ x, const float* __restrict__ bng,
    const float* __restrict__ bnb, const float* __restrict__ bnm,
    const float* __restrict__ bnv, u16* __restrict__ xb)
{
    int g = blockIdx.x * 256 + threadIdx.x;
    if (g >= M_ * (FIN_ / 4)) return;
    int row = g >> 5;
    int n = row % N_;
    float s = bng[n] * rsqrtf(bnv[n] + 1e-5f);
    float sh = bnb[n] - bnm[n] * s;
    float4 v = ((const float4*)x)[g];
    ushort4 o;
    o.x = f2bf(v.x * s + sh);
    o.y = f2bf(v.y * s + sh);
    o.z = f2bf(v.z * s + sh);
    o.w = f2bf(v.w * s + sh);
    ((ushort4*)xb)[g] = o;
}

// ---------------------------------------------------------------------------
// Pack transposed bf16 weights: wmlp_t[n][k]; wgat_t[l][n][k] (n = head*64+d)
// ---------------------------------------------------------------------------
__global__ __launch_bounds__(256) void repack_w(
    const float* __restrict__ Wm, const float* __restrict__ Wg,
    u16* __restrict__ wmlp_t, u16* __restrict__ wgat_t)
{
    int idx = blockIdx.x * 256 + threadIdx.x;
    const int T1 = HID_ * FIN_;
    const int T2 = LAYERS_ * HID_ * HID_;
    if (idx < T1) {
        int n = idx / FIN_, k = idx % FIN_;
        wmlp_t[idx] = f2bf(Wm[k * HID_ + n]);
    } else if (idx < T1 + T2) {
        int j = idx - T1;
        int l = j / (HID_ * HID_);
        int r = j % (HID_ * HID_);
        int n = r / HID_, k = r % HID_;
        wgat_t[j] = f2bf(Wg[(((size_t)(l * HEADS_ + (n >> 6))) * HID_ + k) * FOUT_ + (n & 63)]);
    }
}

// ---------------------------------------------------------------------------
// adjacency -> per-row 64-bit masks, one block per graph
// ---------------------------------------------------------------------------
__global__ __launch_bounds__(256) void build_masks(
    const int* __restrict__ adj, uint64_t* __restrict__ masks)
{
    __shared__ uint32_t m32[128];
    const int b = blockIdx.x, tid = threadIdx.x;
    if (tid < 128) m32[tid] = 0;
    __syncthreads();
    const int* a = adj + (size_t)b * N_ * N_;
    for (int idx = tid; idx < N_ * N_; idx += 256) {
        int i = idx / N_, j = idx % N_;
        if (a[idx] > 0) atomicOr(&m32[i * 2 + (j >> 5)], 1u << (j & 31));
    }
    __syncthreads();
    if (tid < 128) ((uint32_t*)(masks + (size_t)b * 64))[tid] = m32[tid];
}

// ---------------------------------------------------------------------------
// bf16 MFMA GEMM for the MLP (K=128), LDS-staged coalesced epilogue.
// ---------------------------------------------------------------------------
#define CS_STRIDE 136
__global__ __launch_bounds__(256) void gemm_mfma(
    const u16* __restrict__ A, const u16* __restrict__ Bt,
    const float* __restrict__ bias, u16* __restrict__ C,
    int K, int lda)
{
    __shared__ u16 sh[4 * 32 * CS_STRIDE];
    u16* As = sh;
    u16* Bs = sh + 5120;
    const int tid = threadIdx.x;
    const int wave = tid >> 6, lane = tid & 63;
    const int lr = lane & 15, lq = lane >> 4;
    const int bx = blockIdx.x & 3;
    const int by = blockIdx.x >> 2;
    const int row0 = by << 7, col0 = bx << 7;
    const int srow = tid >> 2, skq = tid & 3;

    f32x4 acc[2][8];
#pragma unroll
    for (int mt = 0; mt < 2; mt++)
#pragma unroll
        for (int nt = 0; nt < 8; nt++) acc[mt][nt] = (f32x4){0.f, 0.f, 0.f, 0.f};

    const int arow0 = wave * 32 + lr;
    for (int k0 = 0; k0 < K; k0 += 32) {
        uint4 av[2], bv[2];
#pragma unroll
        for (int it = 0; it < 2; it++) {
            int row = srow + it * 64;
            av[it] = *(const uint4*)(A + (size_t)(row0 + row) * lda + k0 + skq * 8);
            bv[it] = *(const uint4*)(Bt + (size_t)(col0 + row) * K + k0 + skq * 8);
        }
        __syncthreads();
#pragma unroll
        for (int it = 0; it < 2; it++) {
            int row = srow + it * 64;
            *(uint4*)&As[row * 40 + skq * 8] = av[it];
            *(uint4*)&Bs[row * 40 + skq * 8] = bv[it];
        }
        __syncthreads();

        bf16x8 afrag[2], bfrag[8];
        afrag[0] = *(const bf16x8*)&As[(arow0) * 40 + lq * 8];
        afrag[1] = *(const bf16x8*)&As[(arow0 + 16) * 40 + lq * 8];
#pragma unroll
        for (int nt = 0; nt < 8; nt++)
            bfrag[nt] = *(const bf16x8*)&Bs[(nt * 16 + lr) * 40 + lq * 8];
#pragma unroll
        for (int mt = 0; mt < 2; mt++)
#pragma unroll
            for (int nt = 0; nt < 8; nt++)
                acc[mt][nt] = __builtin_amdgcn_mfma_f32_16x16x32_bf16(
                    afrag[mt], bfrag[nt], acc[mt][nt], 0, 0, 0);
    }

    float bl[8];
#pragma unroll
    for (int nt = 0; nt < 8; nt++)
        bl[nt] = bias ? bias[col0 + nt * 16 + lr] : 0.f;

    __syncthreads();
    u16* cs = sh + wave * 32 * CS_STRIDE;
#pragma unroll
    for (int mt = 0; mt < 2; mt++)
#pragma unroll
        for (int nt = 0; nt < 8; nt++)
#pragma unroll
            for (int r = 0; r < 4; r++)
                cs[(mt * 16 + lq * 4 + r) * CS_STRIDE + nt * 16 + lr] =
                    f2bf(acc[mt][nt][r] + bl[nt]);
    __syncthreads();
#pragma unroll
    for (int it = 0; it < 8; it++) {
        int linear = it * 64 + lane;
        int r = linear >> 4, q = linear & 15;
        uint4 v = *(const uint4*)&cs[r * CS_STRIDE + q * 8];
        *(uint4*)(C + (size_t)(row0 + wave * 32 + r) * HID_ + col0 + q * 8) = v;
    }
}

// ---------------------------------------------------------------------------
// Per-layer projection GEMM, graph-aligned: one block per graph, 8 waves,
// wave = head. Stages hx[b] (padded to 64 rows) in LDS per 128-k-chunk,
// W streamed from L2. Output written TRANSPOSED: hTg[b_loc][h][d][j] (bf16),
// j padded to 64 with zeros (A pad rows are zero).
// ---------------------------------------------------------------------------
#define PA_STRIDE 136
__global__ __launch_bounds__(512, 4) void proj_gemm(
    const u16* __restrict__ hx, const u16* __restrict__ Wt,
    u16* __restrict__ hTg)
{
    __shared__ u16 As[64 * PA_STRIDE];   // 17.4 KB
    const int tid = threadIdx.x;
    const int b = blockIdx.x;            // chunk-local graph; hx pre-offset
    const int wave = tid >> 6, lane = tid & 63;
    const int lr = lane & 15, lq = lane >> 4;

    const u16* hxb = hx + (size_t)b * N_ * HID_;

    f32x4 acc[4][4];
#pragma unroll
    for (int mt = 0; mt < 4; mt++)
#pragma unroll
        for (int nt = 0; nt < 4; nt++) acc[mt][nt] = (f32x4){0.f, 0.f, 0.f, 0.f};

    const u16* wp = Wt + (size_t)wave * 64 * HID_;   // head's 64 output cols

    for (int kc = 0; kc < 4; kc++) {      // k-chunks of 128
        __syncthreads();
#pragma unroll
        for (int it = 0; it < 2; it++) {
            int idx = it * 512 + tid;     // 1024 uint4 = 64 rows x 16 q
            int row = idx >> 4, q = idx & 15;
            uint4 v = (uint4){0u, 0u, 0u, 0u};
            if (row < N_)
                v = *(const uint4*)(hxb + (size_t)row * HID_ + kc * 128 + q * 8);
            *(uint4*)&As[row * PA_STRIDE + q * 8] = v;
        }
        __syncthreads();
#pragma unroll
        for (int s = 0; s < 4; s++) {     // k-steps of 32
            bf16x8 af[4];
#pragma unroll
            for (int mt = 0; mt < 4; mt++)
                af[mt] = *(const bf16x8*)&As[(mt * 16 + lr) * PA_STRIDE + s * 32 + lq * 8];
#pragma unroll
            for (int nt = 0; nt < 4; nt++) {
                bf16x8 bfr = *(const bf16x8*)(wp + (size_t)(nt * 16 + lr) * HID_ + kc * 128 + s * 32 + lq * 8);
#pragma unroll
                for (int mt = 0; mt < 4; mt++)
                    acc[mt][nt] = __builtin_amdgcn_mfma_f32_16x16x32_bf16(
                        af[mt], bfr, acc[mt][nt], 0, 0, 0);
            }
        }
    }

    // transposed store: C row = j (node), col = d. Lane's 4 regs = 4
    // consecutive j -> 8B packed stores. hTg[((b*8+h)*64 + d)*64 + j]
    u16* outp = hTg + ((size_t)(b * 8 + wave) * 64) * 64;
#pragma unroll
    for (int nt = 0; nt < 4; nt++) {
        int d = nt * 16 + lr;
#pragma unroll
        for (int mt = 0; mt < 4; mt++) {
            ushort4 v;
            v.x = f2bf(acc[mt][nt][0]);
            v.y = f2bf(acc[mt][nt][1]);
            v.z = f2bf(acc[mt][nt][2]);
            v.w = f2bf(acc[mt][nt][3]);
            *(ushort4*)(outp + d * 64 + mt * 16 + lq * 4) = v;
        }
    }
}

// ---------------------------------------------------------------------------
// Attention: one WAVE per (graph, head) unit, 2 units per 128-thread block.
// Zero barriers — all LDS is wave-private (DS pipe is in-order per wave;
// this cross-lane write->read pattern validated in round 4).
// hTg: [b_loc][h][d(64)][j(64)] bf16 (j 62/63 are zero).
// ---------------------------------------------------------------------------
#define S_HT 72
#define UNIT_U16 5248   // hT 64*72 + f1/f2/c2 (3*64 f32) + msk (64 u64)
__global__ __launch_bounds__(128, 4) void attn(
    const u16* __restrict__ hTg, const uint64_t* __restrict__ masks,
    const float* __restrict__ ag, u16* __restrict__ hx)
{
    __shared__ __align__(16) u16 pool[2 * UNIT_U16];
    const int tid = threadIdx.x;
    const int wu = tid >> 6, lane = tid & 63;
    const int lr = lane & 15, lq = lane >> 4;
    const int unit = blockIdx.x * 2 + wu;
    const int bl = unit >> 3, head = unit & 7;   // chunk-local graph, head

    u16* hT = pool + wu * UNIT_U16;              // [64 d][72] (j in 0..63)
    float* f1s = (float*)(hT + 64 * S_HT);
    float* f2s = f1s + 64;
    float* c2s = f2s + 64;
    uint64_t* msk = (uint64_t*)(c2s + 64);

    // ---- load hT tile (8 KB contiguous) + masks ----
    const u16* src = hTg + (size_t)unit * 4096;
#pragma unroll
    for (int it = 0; it < 8; it++) {
        int idx = it * 64 + lane;
        int d = idx >> 3, q = idx & 7;
        *(uint4*)&hT[d * S_HT + q * 8] = *(const uint4*)(src + d * 64 + q * 8);
    }
    msk[lane] = (lane < N_) ? masks[(size_t)bl * 64 + lane] : 0ull;

    // ---- f1/f2 (lane = node j) ----
    const float* agh = ag + head * 128;
    float p1 = 0.f, p2 = 0.f;
#pragma unroll
    for (int d = 0; d < 64; d++) {
        float hv = bf2f(hT[d * S_HT + lane]);
        p1 += hv * agh[d];
        p2 += hv * agh[64 + d];
    }
    f1s[lane] = p1;
    f2s[lane] = p2;

    // ---- column softmax stats (lane = column j): c2 = m*log2e + log2(s) ----
    {
        float m = -9e15f;
#pragma unroll 2
        for (int i = 0; i < N_; i++) {
            float z = f2s[i] + p1;
            z = fmaxf(z, 0.2f * z);
            float zm = ((msk[i] >> lane) & 1ull) ? z : -9e15f;
            m = fmaxf(m, zm);
        }
        float s = 0.f;
#pragma unroll 2
        for (int i = 0; i < N_; i++) {
            float z = f2s[i] + p1;
            z = fmaxf(z, 0.2f * z);
            float zm = ((msk[i] >> lane) & 1ull) ? z : -9e15f;
            s += __builtin_amdgcn_exp2f((zm - m) * L2E);
        }
        c2s[lane] = m * L2E + __builtin_amdgcn_logf(s);   // v_log_f32 = log2
    }

    // ---- hp = P @ h via MFMA; P A-fragments built on the fly ----
    f32x4 acc[4][4];
#pragma unroll
    for (int it = 0; it < 4; it++)
#pragma unroll
        for (int dt = 0; dt < 4; dt++) acc[it][dt] = (f32x4){0.f, 0.f, 0.f, 0.f};

#pragma unroll
    for (int kt = 0; kt < 2; kt++) {
        int j0 = kt * 32 + lq * 8;
        float4 f1a = *(const float4*)&f1s[j0];
        float4 f1b = *(const float4*)&f1s[j0 + 4];
        float4 c2a = *(const float4*)&c2s[j0];
        float4 c2b = *(const float4*)&c2s[j0 + 4];
        float f1v[8] = {f1a.x, f1a.y, f1a.z, f1a.w, f1b.x, f1b.y, f1b.z, f1b.w};
        float cv[8]  = {c2a.x, c2a.y, c2a.z, c2a.w, c2b.x, c2b.y, c2b.z, c2b.w};
        bf16x8 hb[4];
#pragma unroll
        for (int dt = 0; dt < 4; dt++)
            hb[dt] = *(const bf16x8*)&hT[(dt * 16 + lr) * S_HT + kt * 32 + lq * 8];
#pragma unroll
        for (int it = 0; it < 4; it++) {
            int i = it * 16 + lr;
            float f2i = f2s[i];
            uint64_t mi = msk[i];
            bf16x8 pf;
#pragma unroll
            for (int t = 0; t < 8; t++) {
                float z = f2i + f1v[t];
                z = fmaxf(z, 0.2f * z);
                float zm = ((mi >> (j0 + t)) & 1ull) ? z : -9e15f;
                float arg = fminf(zm * L2E - cv[t], 0.f);
                pf[t] = (__bf16)__builtin_amdgcn_exp2f(arg);
            }
#pragma unroll
            for (int dt = 0; dt < 4; dt++)
                acc[it][dt] = __builtin_amdgcn_mfma_f32_16x16x32_bf16(
                    pf, hb[dt], acc[it][dt], 0, 0, 0);
        }
    }

    // ---- ELU -> LDS row-major (reuse hT region; DS ops are in-order) ----
#pragma unroll
    for (int it = 0; it < 4; it++)
#pragma unroll
        for (int dt = 0; dt < 4; dt++)
#pragma unroll
            for (int r = 0; r < 4; r++) {
                float v = acc[it][dt][r];
                v = v > 0.f ? v : __builtin_amdgcn_exp2f(v * L2E) - 1.f;
                hT[(it * 16 + lq * 4 + r) * S_HT + dt * 16 + lr] = f2bf(v);
            }

    // ---- coalesced store: rows 0..61, 128B per row at this head's columns
    u16* dst = hx + ((size_t)bl * N_) * HID_ + head * FOUT_;
#pragma unroll
    for (int it = 0; it < 8; it++) {
        int idx = it * 64 + lane;
        int row = idx >> 3, q = idx & 7;
        if (row < N_)
            *(uint4*)(dst + (size_t)row * HID_ + q * 8) =
                *(const uint4*)&hT[row * S_HT + q * 8];
    }
}

// ---------------------------------------------------------------------------
// pooled[b,:] = sum_n hx[b,n,:]; logits = pooled @ W_out + b_out; log_softmax
// ---------------------------------------------------------------------------
__global__ __launch_bounds__(256) void pool_out(
    const u16* __restrict__ hx, const float* __restrict__ Wout,
    const float* __restrict__ bout, float* __restrict__ out)
{
    __shared__ float pooled[HID_];
    __shared__ float lg[3];
    const int tid = threadIdx.x;
    const int b = blockIdx.x;
    const u16* hb = hx + (size_t)b * N_ * HID_;
    for (int f = tid; f < HID_; f += 256) {
        float s = 0.f;
        for (int n = 0; n < N_; n++) s += bf2f(hb[n * HID_ + f]);
        pooled[f] = s;
    }
    __syncthreads();
    if (tid < 192) {
        int c = tid >> 6, lane = tid & 63;
        float p = 0.f;
        for (int k = lane; k < HID_; k += 64) p += pooled[k] * Wout[k * 3 + c];
        for (int off = 32; off > 0; off >>= 1) p += __shfl_down(p, off, 64);
        if (lane == 0) lg[c] = p + bout[c];
    }
    __syncthreads();
    if (tid == 0) {
        float l0 = lg[0], l1 = lg[1], l2 = lg[2];
        float m = fmaxf(l0, fmaxf(l1, l2));
        float s = __expf(l0 - m) + __expf(l1 - m) + __expf(l2 - m);
        float ls = m + logf(s);
        out[b * 3 + 0] = l0 - ls;
        out[b * 3 + 1] = l1 - ls;
        out[b * 3 + 2] = l2 - ls;
    }
}

// ---------------------------------------------------------------------------
extern "C" void kernel_launch(void* const* d_in, const int* in_sizes, int n_in,
                              void* d_out, int out_size, void* d_ws, size_t ws_size,
                              hipStream_t stream)
{
    const float* x   = (const float*)d_in[0];
    const int*   adj = (const int*)d_in[1];
    const float* bng = (const float*)d_in[2];
    const float* bnb = (const float*)d_in[3];
    const float* bnm = (const float*)d_in[4];
    const float* bnv = (const float*)d_in[5];
    const float* Wm  = (const float*)d_in[6];
    const float* bm  = (const float*)d_in[7];
    const float* Wg  = (const float*)d_in[8];
    const float* ag  = (const float*)d_in[9];
    const float* Wo  = (const float*)d_in[10];
    const float* bo  = (const float*)d_in[11];
    float* out = (float*)d_out;

    // ws layout: xb (16.25M u16; reused as hTg chunks of 8.39M u16 after MLP)
    //            | hx | masks | wmlp_t | wgat_t   (~165 MB total)
    u16* xb = (u16*)d_ws;
    u16* hTg = xb;                                   // alias: xb dead after MLP
    u16* hx = xb + (size_t)M_ * FIN_;
    uint64_t* masks = (uint64_t*)(hx + (size_t)M_ * HID_);
    u16* wmlp_t = (u16*)(masks + (size_t)B_ * 64);
    u16* wgat_t = wmlp_t + (size_t)HID_ * FIN_;

    bn_cast<<<(M_ * (FIN_ / 4) + 255) / 256, 256, 0, stream>>>(x, bng, bnb, bnm, bnv, xb);

    int rep_total = HID_ * FIN_ + LAYERS_ * HID_ * HID_;
    repack_w<<<(rep_total + 255) / 256, 256, 0, stream>>>(Wm, Wg, wmlp_t, wgat_t);

    build_masks<<<B_, 256, 0, stream>>>(adj, masks);

    // MLP: hx = xb @ W_mlp + b_mlp
    gemm_mfma<<<(M_ / 128) * 4, 256, 0, stream>>>(xb, wmlp_t, bm, hx, FIN_, FIN_);

    for (int l = 0; l < LAYERS_; l++) {
        const u16* wt = wgat_t + (size_t)l * HID_ * HID_;
        const float* agl = ag + (size_t)l * HEADS_ * 2 * FOUT_;
        for (int c = 0; c < B_ / CHG_; c++) {
            u16* hxc = hx + (size_t)c * CHG_ * N_ * HID_;
            const uint64_t* mc = masks + (size_t)c * CHG_ * 64;
            proj_gemm<<<CHG_, 512, 0, stream>>>(hxc, wt, hTg);
            attn<<<CHG_ * HEADS_ / 2, 128, 0, stream>>>(hTg, mc, agl, hxc);
        }
    }
    pool_out<<<B_, 256, 0, stream>>>(hx, Wo, bo, out);
}

// Round 7
// 1171.438 us; speedup vs baseline: 1.2870x; 1.2870x over previous
//
#include <hip/hip_runtime.h>
#include <cstdint>
#include <cstddef>

#define B_ 2048
#define N_ 62
#define FIN_ 128
#define HID_ 512
#define HEADS_ 8
#define FOUT_ 64
#define LAYERS_ 3
#define M_ (B_*N_)           // 126976
#define L2E 1.44269504f

typedef __bf16 bf16x8 __attribute__((ext_vector_type(8)));
typedef float  f32x4  __attribute__((ext_vector_type(4)));
typedef unsigned short u16;

static __device__ __forceinline__ u16 f2bf(float f) {
    union { float f; uint32_t u; } v; v.f = f;
    uint32_t u = v.u;
    return (u16)((u + 0x7fffu + ((u >> 16) & 1u)) >> 16);
}
static __device__ __forceinline__ float bf2f(u16 s) {
    union { uint32_t u; float f; } v; v.u = ((uint32_t)s) << 16;
    return v.f;
}

// ---------------------------------------------------------------------------
// xb = BN(x) cast to bf16
// ---------------------------------------------------------------------------
__global__ __launch_bounds__(256) void bn_cast(
    const float* __restrict__ x, const float* __restrict__ bng,
    const float* __restrict__ bnb, const float* __restrict__ bnm,
    const float* __restrict__ bnv, u16* __restrict__ xb)
{
    int g = blockIdx.x * 256 + threadIdx.x;
    if (g >= M_ * (FIN_ / 4)) return;
    int row = g >> 5;
    int n = row % N_;
    float s = bng[n] * rsqrtf(bnv[n] + 1e-5f);
    float sh = bnb[n] - bnm[n] * s;
    float4 v = ((const float4*)x)[g];
    ushort4 o;
    o.x = f2bf(v.x * s + sh);
    o.y = f2bf(v.y * s + sh);
    o.z = f2bf(v.z * s + sh);
    o.w = f2bf(v.w * s + sh);
    ((ushort4*)xb)[g] = o;
}

// ---------------------------------------------------------------------------
// Pack transposed bf16 weights: wmlp_t[n][k]; wgat_t[l][n][k] (n = head*64+d)
// ---------------------------------------------------------------------------
__global__ __launch_bounds__(256) void repack_w(
    const float* __restrict__ Wm, const float* __restrict__ Wg,
    u16* __restrict__ wmlp_t, u16* __restrict__ wgat_t)
{
    int idx = blockIdx.x * 256 + threadIdx.x;
    const int T1 = HID_ * FIN_;
    const int T2 = LAYERS_ * HID_ * HID_;
    if (idx < T1) {
        int n = idx / FIN_, k = idx % FIN_;
        wmlp_t[idx] = f2bf(Wm[k * HID_ + n]);
    } else if (idx < T1 + T2) {
        int j = idx - T1;
        int l = j / (HID_ * HID_);
        int r = j % (HID_ * HID_);
        int n = r / HID_, k = r % HID_;
        wgat_t[j] = f2bf(Wg[(((size_t)(l * HEADS_ + (n >> 6))) * HID_ + k) * FOUT_ + (n & 63)]);
    }
}

// ---------------------------------------------------------------------------
// adjacency -> per-row 64-bit masks, one block per graph
// ---------------------------------------------------------------------------
__global__ __launch_bounds__(256) void build_masks(
    const int* __restrict__ adj, uint64_t* __restrict__ masks)
{
    __shared__ uint32_t m32[128];
    const int b = blockIdx.x, tid = threadIdx.x;
    if (tid < 128) m32[tid] = 0;
    __syncthreads();
    const int* a = adj + (size_t)b * N_ * N_;
    for (int idx = tid; idx < N_ * N_; idx += 256) {
        int i = idx / N_, j = idx % N_;
        if (a[idx] > 0) atomicOr(&m32[i * 2 + (j >> 5)], 1u << (j & 31));
    }
    __syncthreads();
    if (tid < 128) ((uint32_t*)(masks + (size_t)b * 64))[tid] = m32[tid];
}

// ---------------------------------------------------------------------------
// bf16 MFMA GEMM for the MLP (K=128), LDS-staged coalesced epilogue.
// COL-MAJOR block ordering: the 4 col-blocks of a row group are 992 apart in
// blockIdx -> same XCD (992 % 8 == 0) -> full 1024-B C rows merge in ONE L2
// before HBM writeback (tests the cross-XCD partial-line write-amp theory).
// ---------------------------------------------------------------------------
#define CS_STRIDE 136
#define NBY_ (M_ / 128)   // 992
__global__ __launch_bounds__(256) void gemm_mfma(
    const u16* __restrict__ A, const u16* __restrict__ Bt,
    const float* __restrict__ bias, u16* __restrict__ C,
    int K, int lda)
{
    __shared__ u16 sh[4 * 32 * CS_STRIDE];
    u16* As = sh;
    u16* Bs = sh + 5120;
    const int tid = threadIdx.x;
    const int wave = tid >> 6, lane = tid & 63;
    const int lr = lane & 15, lq = lane >> 4;
    const int by = blockIdx.x % NBY_;        // col-major ordering
    const int bx = blockIdx.x / NBY_;
    const int row0 = by << 7, col0 = bx << 7;
    const int srow = tid >> 2, skq = tid & 3;

    f32x4 acc[2][8];
#pragma unroll
    for (int mt = 0; mt < 2; mt++)
#pragma unroll
        for (int nt = 0; nt < 8; nt++) acc[mt][nt] = (f32x4){0.f, 0.f, 0.f, 0.f};

    const int arow0 = wave * 32 + lr;
    for (int k0 = 0; k0 < K; k0 += 32) {
        uint4 av[2], bv[2];
#pragma unroll
        for (int it = 0; it < 2; it++) {
            int row = srow + it * 64;
            av[it] = *(const uint4*)(A + (size_t)(row0 + row) * lda + k0 + skq * 8);
            bv[it] = *(const uint4*)(Bt + (size_t)(col0 + row) * K + k0 + skq * 8);
        }
        __syncthreads();
#pragma unroll
        for (int it = 0; it < 2; it++) {
            int row = srow + it * 64;
            *(uint4*)&As[row * 40 + skq * 8] = av[it];
            *(uint4*)&Bs[row * 40 + skq * 8] = bv[it];
        }
        __syncthreads();

        bf16x8 afrag[2], bfrag[8];
        afrag[0] = *(const bf16x8*)&As[(arow0) * 40 + lq * 8];
        afrag[1] = *(const bf16x8*)&As[(arow0 + 16) * 40 + lq * 8];
#pragma unroll
        for (int nt = 0; nt < 8; nt++)
            bfrag[nt] = *(const bf16x8*)&Bs[(nt * 16 + lr) * 40 + lq * 8];
#pragma unroll
        for (int mt = 0; mt < 2; mt++)
#pragma unroll
            for (int nt = 0; nt < 8; nt++)
                acc[mt][nt] = __builtin_amdgcn_mfma_f32_16x16x32_bf16(
                    afrag[mt], bfrag[nt], acc[mt][nt], 0, 0, 0);
    }

    float bl[8];
#pragma unroll
    for (int nt = 0; nt < 8; nt++)
        bl[nt] = bias ? bias[col0 + nt * 16 + lr] : 0.f;

    __syncthreads();
    u16* cs = sh + wave * 32 * CS_STRIDE;
#pragma unroll
    for (int mt = 0; mt < 2; mt++)
#pragma unroll
        for (int nt = 0; nt < 8; nt++)
#pragma unroll
            for (int r = 0; r < 4; r++)
                cs[(mt * 16 + lq * 4 + r) * CS_STRIDE + nt * 16 + lr] =
                    f2bf(acc[mt][nt][r] + bl[nt]);
    __syncthreads();
#pragma unroll
    for (int it = 0; it < 8; it++) {
        int linear = it * 64 + lane;
        int r = linear >> 4, q = linear & 15;
        uint4 v = *(const uint4*)&cs[r * CS_STRIDE + q * 8];
        *(uint4*)(C + (size_t)(row0 + wave * 32 + r) * HID_ + col0 + q * 8) = v;
    }
}

// ---------------------------------------------------------------------------
// Per-layer projection GEMM, graph-aligned: one block per graph, 8 waves,
// wave = head. Output TRANSPOSED: hTg[b_loc][h][d][j], j padded to 64.
// ---------------------------------------------------------------------------
#define PA_STRIDE 136
__global__ __launch_bounds__(512, 4) void proj_gemm(
    const u16* __restrict__ hx, const u16* __restrict__ Wt,
    u16* __restrict__ hTg)
{
    __shared__ u16 As[64 * PA_STRIDE];   // 17.4 KB
    const int tid = threadIdx.x;
    const int b = blockIdx.x;            // chunk-local graph; hx pre-offset
    const int wave = tid >> 6, lane = tid & 63;
    const int lr = lane & 15, lq = lane >> 4;

    const u16* hxb = hx + (size_t)b * N_ * HID_;

    f32x4 acc[4][4];
#pragma unroll
    for (int mt = 0; mt < 4; mt++)
#pragma unroll
        for (int nt = 0; nt < 4; nt++) acc[mt][nt] = (f32x4){0.f, 0.f, 0.f, 0.f};

    const u16* wp = Wt + (size_t)wave * 64 * HID_;

    for (int kc = 0; kc < 4; kc++) {      // k-chunks of 128
        __syncthreads();
#pragma unroll
        for (int it = 0; it < 2; it++) {
            int idx = it * 512 + tid;
            int row = idx >> 4, q = idx & 15;
            uint4 v = (uint4){0u, 0u, 0u, 0u};
            if (row < N_)
                v = *(const uint4*)(hxb + (size_t)row * HID_ + kc * 128 + q * 8);
            *(uint4*)&As[row * PA_STRIDE + q * 8] = v;
        }
        __syncthreads();
#pragma unroll
        for (int s = 0; s < 4; s++) {
            bf16x8 af[4];
#pragma unroll
            for (int mt = 0; mt < 4; mt++)
                af[mt] = *(const bf16x8*)&As[(mt * 16 + lr) * PA_STRIDE + s * 32 + lq * 8];
#pragma unroll
            for (int nt = 0; nt < 4; nt++) {
                bf16x8 bfr = *(const bf16x8*)(wp + (size_t)(nt * 16 + lr) * HID_ + kc * 128 + s * 32 + lq * 8);
#pragma unroll
                for (int mt = 0; mt < 4; mt++)
                    acc[mt][nt] = __builtin_amdgcn_mfma_f32_16x16x32_bf16(
                        af[mt], bfr, acc[mt][nt], 0, 0, 0);
            }
        }
    }

    u16* outp = hTg + ((size_t)(b * 8 + wave) * 64) * 64;
#pragma unroll
    for (int nt = 0; nt < 4; nt++) {
        int d = nt * 16 + lr;
#pragma unroll
        for (int mt = 0; mt < 4; mt++) {
            ushort4 v;
            v.x = f2bf(acc[mt][nt][0]);
            v.y = f2bf(acc[mt][nt][1]);
            v.z = f2bf(acc[mt][nt][2]);
            v.w = f2bf(acc[mt][nt][3]);
            *(ushort4*)(outp + d * 64 + mt * 16 + lq * 4) = v;
        }
    }
}

// ---------------------------------------------------------------------------
// Attention: one WAVE per (graph, head); 4 units per 256-thread block,
// grouped so a block covers heads {0-3} or {4-7} of ONE graph -> its hx
// writes form 512-B row segments from a single XCD. Zero barriers.
// ---------------------------------------------------------------------------
#define S_HT 72
#define UNIT_U16 5248   // hT 64*72 + f1/f2/c2 (3*64 f32) + msk (64 u64)
__global__ __launch_bounds__(256, 4) void attn(
    const u16* __restrict__ hTg, const uint64_t* __restrict__ masks,
    const float* __restrict__ ag, u16* __restrict__ hx)
{
    __shared__ __align__(16) u16 pool[4 * UNIT_U16];   // 42 KB
    const int tid = threadIdx.x;
    const int wu = tid >> 6, lane = tid & 63;
    const int lr = lane & 15, lq = lane >> 4;
    const int bl = blockIdx.x >> 1;                 // chunk-local graph
    const int head = (blockIdx.x & 1) * 4 + wu;
    const int unit = bl * 8 + head;

    u16* hT = pool + wu * UNIT_U16;
    float* f1s = (float*)(hT + 64 * S_HT);
    float* f2s = f1s + 64;
    float* c2s = f2s + 64;
    uint64_t* msk = (uint64_t*)(c2s + 64);

    // ---- load hT tile (8 KB contiguous) + masks ----
    const u16* src = hTg + (size_t)unit * 4096;
#pragma unroll
    for (int it = 0; it < 8; it++) {
        int idx = it * 64 + lane;
        int d = idx >> 3, q = idx & 7;
        *(uint4*)&hT[d * S_HT + q * 8] = *(const uint4*)(src + d * 64 + q * 8);
    }
    msk[lane] = (lane < N_) ? masks[(size_t)bl * 64 + lane] : 0ull;

    // ---- f1/f2 (lane = node j) ----
    const float* agh = ag + head * 128;
    float p1 = 0.f, p2 = 0.f;
#pragma unroll
    for (int d = 0; d < 64; d++) {
        float hv = bf2f(hT[d * S_HT + lane]);
        p1 += hv * agh[d];
        p2 += hv * agh[64 + d];
    }
    f1s[lane] = p1;
    f2s[lane] = p2;

    // ---- column softmax stats (lane = column j): c2 = m*log2e + log2(s) ----
    {
        float m = -9e15f;
#pragma unroll 2
        for (int i = 0; i < N_; i++) {
            float z = f2s[i] + p1;
            z = fmaxf(z, 0.2f * z);
            float zm = ((msk[i] >> lane) & 1ull) ? z : -9e15f;
            m = fmaxf(m, zm);
        }
        float s = 0.f;
#pragma unroll 2
        for (int i = 0; i < N_; i++) {
            float z = f2s[i] + p1;
            z = fmaxf(z, 0.2f * z);
            float zm = ((msk[i] >> lane) & 1ull) ? z : -9e15f;
            s += __builtin_amdgcn_exp2f((zm - m) * L2E);
        }
        c2s[lane] = m * L2E + __builtin_amdgcn_logf(s);   // v_log_f32 = log2
    }

    // ---- hp = P @ h via MFMA; P A-fragments built on the fly ----
    f32x4 acc[4][4];
#pragma unroll
    for (int it = 0; it < 4; it++)
#pragma unroll
        for (int dt = 0; dt < 4; dt++) acc[it][dt] = (f32x4){0.f, 0.f, 0.f, 0.f};

#pragma unroll
    for (int kt = 0; kt < 2; kt++) {
        int j0 = kt * 32 + lq * 8;
        float4 f1a = *(const float4*)&f1s[j0];
        float4 f1b = *(const float4*)&f1s[j0 + 4];
        float4 c2a = *(const float4*)&c2s[j0];
        float4 c2b = *(const float4*)&c2s[j0 + 4];
        float f1v[8] = {f1a.x, f1a.y, f1a.z, f1a.w, f1b.x, f1b.y, f1b.z, f1b.w};
        float cv[8]  = {c2a.x, c2a.y, c2a.z, c2a.w, c2b.x, c2b.y, c2b.z, c2b.w};
        bf16x8 hb[4];
#pragma unroll
        for (int dt = 0; dt < 4; dt++)
            hb[dt] = *(const bf16x8*)&hT[(dt * 16 + lr) * S_HT + kt * 32 + lq * 8];
#pragma unroll
        for (int it = 0; it < 4; it++) {
            int i = it * 16 + lr;
            float f2i = f2s[i];
            uint64_t mi = msk[i];
            bf16x8 pf;
#pragma unroll
            for (int t = 0; t < 8; t++) {
                float z = f2i + f1v[t];
                z = fmaxf(z, 0.2f * z);
                float zm = ((mi >> (j0 + t)) & 1ull) ? z : -9e15f;
                float arg = fminf(zm * L2E - cv[t], 0.f);
                pf[t] = (__bf16)__builtin_amdgcn_exp2f(arg);
            }
#pragma unroll
            for (int dt = 0; dt < 4; dt++)
                acc[it][dt] = __builtin_amdgcn_mfma_f32_16x16x32_bf16(
                    pf, hb[dt], acc[it][dt], 0, 0, 0);
        }
    }

    // ---- ELU -> LDS row-major (reuse hT region; DS ops in-order per wave) --
#pragma unroll
    for (int it = 0; it < 4; it++)
#pragma unroll
        for (int dt = 0; dt < 4; dt++)
#pragma unroll
            for (int r = 0; r < 4; r++) {
                float v = acc[it][dt][r];
                v = v > 0.f ? v : __builtin_amdgcn_exp2f(v * L2E) - 1.f;
                hT[(it * 16 + lq * 4 + r) * S_HT + dt * 16 + lr] = f2bf(v);
            }

    // ---- coalesced store: rows 0..61, 128B per row at this head's columns
    u16* dst = hx + ((size_t)bl * N_) * HID_ + head * FOUT_;
#pragma unroll
    for (int it = 0; it < 8; it++) {
        int idx = it * 64 + lane;
        int row = idx >> 3, q = idx & 7;
        if (row < N_)
            *(uint4*)(dst + (size_t)row * HID_ + q * 8) =
                *(const uint4*)&hT[row * S_HT + q * 8];
    }
}

// ---------------------------------------------------------------------------
// pooled[b,:] = sum_n hx[b,n,:]; logits = pooled @ W_out + b_out; log_softmax
// ---------------------------------------------------------------------------
__global__ __launch_bounds__(256) void pool_out(
    const u16* __restrict__ hx, const float* __restrict__ Wout,
    const float* __restrict__ bout, float* __restrict__ out)
{
    __shared__ float pooled[HID_];
    __shared__ float lg[3];
    const int tid = threadIdx.x;
    const int b = blockIdx.x;
    const u16* hb = hx + (size_t)b * N_ * HID_;
    for (int f = tid; f < HID_; f += 256) {
        float s = 0.f;
        for (int n = 0; n < N_; n++) s += bf2f(hb[n * HID_ + f]);
        pooled[f] = s;
    }
    __syncthreads();
    if (tid < 192) {
        int c = tid >> 6, lane = tid & 63;
        float p = 0.f;
        for (int k = lane; k < HID_; k += 64) p += pooled[k] * Wout[k * 3 + c];
        for (int off = 32; off > 0; off >>= 1) p += __shfl_down(p, off, 64);
        if (lane == 0) lg[c] = p + bout[c];
    }
    __syncthreads();
    if (tid == 0) {
        float l0 = lg[0], l1 = lg[1], l2 = lg[2];
        float m = fmaxf(l0, fmaxf(l1, l2));
        float s = __expf(l0 - m) + __expf(l1 - m) + __expf(l2 - m);
        float ls = m + logf(s);
        out[b * 3 + 0] = l0 - ls;
        out[b * 3 + 1] = l1 - ls;
        out[b * 3 + 2] = l2 - ls;
    }
}

// ---------------------------------------------------------------------------
extern "C" void kernel_launch(void* const* d_in, const int* in_sizes, int n_in,
                              void* d_out, int out_size, void* d_ws, size_t ws_size,
                              hipStream_t stream)
{
    const float* x   = (const float*)d_in[0];
    const int*   adj = (const int*)d_in[1];
    const float* bng = (const float*)d_in[2];
    const float* bnb = (const float*)d_in[3];
    const float* bnm = (const float*)d_in[4];
    const float* bnv = (const float*)d_in[5];
    const float* Wm  = (const float*)d_in[6];
    const float* bm  = (const float*)d_in[7];
    const float* Wg  = (const float*)d_in[8];
    const float* ag  = (const float*)d_in[9];
    const float* Wo  = (const float*)d_in[10];
    const float* bo  = (const float*)d_in[11];
    float* out = (float*)d_out;

    // ws layout: xb | hx | masks | wmlp_t | wgat_t | hTg (adaptive size)
    u16* xb = (u16*)d_ws;
    u16* hx = xb + (size_t)M_ * FIN_;
    uint64_t* masks = (uint64_t*)(hx + (size_t)M_ * HID_);
    u16* wmlp_t = (u16*)(masks + (size_t)B_ * 64);
    u16* wgat_t = wmlp_t + (size_t)HID_ * FIN_;
    u16* hTg = wgat_t + (size_t)LAYERS_ * HID_ * HID_;

    // fixed part = 165,281,792 B; hTg needs chg*65536 B. ws_size is constant
    // across calls -> this branch is deterministic (graph-capture safe).
    const size_t fixed_b = (size_t)M_ * FIN_ * 2 + (size_t)M_ * HID_ * 2
                         + (size_t)B_ * 64 * 8
                         + ((size_t)HID_ * FIN_ + (size_t)LAYERS_ * HID_ * HID_) * 2;
    size_t rem = (ws_size > fixed_b) ? ws_size - fixed_b : 0;
    int chg = 256;
    if (rem >= (size_t)2048 * 65536) chg = 2048;
    else if (rem >= (size_t)1024 * 65536) chg = 1024;
    else if (rem >= (size_t)512 * 65536) chg = 512;

    bn_cast<<<(M_ * (FIN_ / 4) + 255) / 256, 256, 0, stream>>>(x, bng, bnb, bnm, bnv, xb);

    int rep_total = HID_ * FIN_ + LAYERS_ * HID_ * HID_;
    repack_w<<<(rep_total + 255) / 256, 256, 0, stream>>>(Wm, Wg, wmlp_t, wgat_t);

    build_masks<<<B_, 256, 0, stream>>>(adj, masks);

    // MLP: hx = xb @ W_mlp + b_mlp (col-major block order, grid = 992*4)
    gemm_mfma<<<NBY_ * 4, 256, 0, stream>>>(xb, wmlp_t, bm, hx, FIN_, FIN_);

    for (int l = 0; l < LAYERS_; l++) {
        const u16* wt = wgat_t + (size_t)l * HID_ * HID_;
        const float* agl = ag + (size_t)l * HEADS_ * 2 * FOUT_;
        for (int c = 0; c < B_ / chg; c++) {
            u16* hxc = hx + (size_t)c * chg * N_ * HID_;
            const uint64_t* mc = masks + (size_t)c * chg * 64;
            proj_gemm<<<chg, 512, 0, stream>>>(hxc, wt, hTg);
            attn<<<chg * 2, 256, 0, stream>>>(hTg, mc, agl, hxc);
        }
    }
    pool_out<<<B_, 256, 0, stream>>>(hx, Wo, bo, out);
}

// Round 8
// 1098.913 us; speedup vs baseline: 1.3719x; 1.0660x over previous
//
#include <hip/hip_runtime.h>
#include <cstdint>
#include <cstddef>

#define B_ 2048
#define N_ 62
#define FIN_ 128
#define HID_ 512
#define HEADS_ 8
#define FOUT_ 64
#define LAYERS_ 3
#define M_ (B_*N_)           // 126976
#define L2E 1.44269504f

typedef __bf16 bf16x8 __attribute__((ext_vector_type(8)));
typedef float  f32x4  __attribute__((ext_vector_type(4)));
typedef unsigned short u16;

static __device__ __forceinline__ u16 f2bf(float f) {
    union { float f; uint32_t u; } v; v.f = f;
    uint32_t u = v.u;
    return (u16)((u + 0x7fffu + ((u >> 16) & 1u)) >> 16);
}
static __device__ __forceinline__ float bf2f(u16 s) {
    union { uint32_t u; float f; } v; v.u = ((uint32_t)s) << 16;
    return v.f;
}

// ---------------------------------------------------------------------------
// xb = BN(x) cast to bf16
// ---------------------------------------------------------------------------
__global__ __launch_bounds__(256) void bn_cast(
    const float* __restrict__ x, const float* __restrict__ bng,
    const float* __restrict__ bnb, const float* __restrict__ bnm,
    const float* __restrict__ bnv, u16* __restrict__ xb)
{
    int g = blockIdx.x * 256 + threadIdx.x;
    if (g >= M_ * (FIN_ / 4)) return;
    int row = g >> 5;
    int n = row % N_;
    float s = bng[n] * rsqrtf(bnv[n] + 1e-5f);
    float sh = bnb[n] - bnm[n] * s;
    float4 v = ((const float4*)x)[g];
    ushort4 o;
    o.x = f2bf(v.x * s + sh);
    o.y = f2bf(v.y * s + sh);
    o.z = f2bf(v.z * s + sh);
    o.w = f2bf(v.w * s + sh);
    ((ushort4*)xb)[g] = o;
}

// ---------------------------------------------------------------------------
// Pack transposed bf16 weights: wmlp_t[n][k]; wgat_t[l][n][k] (n = head*64+d)
// ---------------------------------------------------------------------------
__global__ __launch_bounds__(256) void repack_w(
    const float* __restrict__ Wm, const float* __restrict__ Wg,
    u16* __restrict__ wmlp_t, u16* __restrict__ wgat_t)
{
    int idx = blockIdx.x * 256 + threadIdx.x;
    const int T1 = HID_ * FIN_;
    const int T2 = LAYERS_ * HID_ * HID_;
    if (idx < T1) {
        int n = idx / FIN_, k = idx % FIN_;
        wmlp_t[idx] = f2bf(Wm[k * HID_ + n]);
    } else if (idx < T1 + T2) {
        int j = idx - T1;
        int l = j / (HID_ * HID_);
        int r = j % (HID_ * HID_);
        int n = r / HID_, k = r % HID_;
        wgat_t[j] = f2bf(Wg[(((size_t)(l * HEADS_ + (n >> 6))) * HID_ + k) * FOUT_ + (n & 63)]);
    }
}

// ---------------------------------------------------------------------------
// adjacency -> per-row 64-bit masks, one block per graph
// ---------------------------------------------------------------------------
__global__ __launch_bounds__(256) void build_masks(
    const int* __restrict__ adj, uint64_t* __restrict__ masks)
{
    __shared__ uint32_t m32[128];
    const int b = blockIdx.x, tid = threadIdx.x;
    if (tid < 128) m32[tid] = 0;
    __syncthreads();
    const int* a = adj + (size_t)b * N_ * N_;
    for (int idx = tid; idx < N_ * N_; idx += 256) {
        int i = idx / N_, j = idx % N_;
        if (a[idx] > 0) atomicOr(&m32[i * 2 + (j >> 5)], 1u << (j & 31));
    }
    __syncthreads();
    if (tid < 128) ((uint32_t*)(masks + (size_t)b * 64))[tid] = m32[tid];
}

// ---------------------------------------------------------------------------
// bf16 MFMA GEMM for the MLP (K=128), LDS-staged coalesced epilogue,
// col-major block ordering (XCD write-locality).
// ---------------------------------------------------------------------------
#define CS_STRIDE 136
#define NBY_ (M_ / 128)   // 992
__global__ __launch_bounds__(256) void gemm_mfma(
    const u16* __restrict__ A, const u16* __restrict__ Bt,
    const float* __restrict__ bias, u16* __restrict__ C,
    int K, int lda)
{
    __shared__ u16 sh[4 * 32 * CS_STRIDE];
    u16* As = sh;
    u16* Bs = sh + 5120;
    const int tid = threadIdx.x;
    const int wave = tid >> 6, lane = tid & 63;
    const int lr = lane & 15, lq = lane >> 4;
    const int by = blockIdx.x % NBY_;
    const int bx = blockIdx.x / NBY_;
    const int row0 = by << 7, col0 = bx << 7;
    const int srow = tid >> 2, skq = tid & 3;

    f32x4 acc[2][8];
#pragma unroll
    for (int mt = 0; mt < 2; mt++)
#pragma unroll
        for (int nt = 0; nt < 8; nt++) acc[mt][nt] = (f32x4){0.f, 0.f, 0.f, 0.f};

    const int arow0 = wave * 32 + lr;
    for (int k0 = 0; k0 < K; k0 += 32) {
        uint4 av[2], bv[2];
#pragma unroll
        for (int it = 0; it < 2; it++) {
            int row = srow + it * 64;
            av[it] = *(const uint4*)(A + (size_t)(row0 + row) * lda + k0 + skq * 8);
            bv[it] = *(const uint4*)(Bt + (size_t)(col0 + row) * K + k0 + skq * 8);
        }
        __syncthreads();
#pragma unroll
        for (int it = 0; it < 2; it++) {
            int row = srow + it * 64;
            *(uint4*)&As[row * 40 + skq * 8] = av[it];
            *(uint4*)&Bs[row * 40 + skq * 8] = bv[it];
        }
        __syncthreads();

        bf16x8 afrag[2], bfrag[8];
        afrag[0] = *(const bf16x8*)&As[(arow0) * 40 + lq * 8];
        afrag[1] = *(const bf16x8*)&As[(arow0 + 16) * 40 + lq * 8];
#pragma unroll
        for (int nt = 0; nt < 8; nt++)
            bfrag[nt] = *(const bf16x8*)&Bs[(nt * 16 + lr) * 40 + lq * 8];
#pragma unroll
        for (int mt = 0; mt < 2; mt++)
#pragma unroll
            for (int nt = 0; nt < 8; nt++)
                acc[mt][nt] = __builtin_amdgcn_mfma_f32_16x16x32_bf16(
                    afrag[mt], bfrag[nt], acc[mt][nt], 0, 0, 0);
    }

    float bl[8];
#pragma unroll
    for (int nt = 0; nt < 8; nt++)
        bl[nt] = bias ? bias[col0 + nt * 16 + lr] : 0.f;

    __syncthreads();
    u16* cs = sh + wave * 32 * CS_STRIDE;
#pragma unroll
    for (int mt = 0; mt < 2; mt++)
#pragma unroll
        for (int nt = 0; nt < 8; nt++)
#pragma unroll
            for (int r = 0; r < 4; r++)
                cs[(mt * 16 + lq * 4 + r) * CS_STRIDE + nt * 16 + lr] =
                    f2bf(acc[mt][nt][r] + bl[nt]);
    __syncthreads();
#pragma unroll
    for (int it = 0; it < 8; it++) {
        int linear = it * 64 + lane;
        int r = linear >> 4, q = linear & 15;
        uint4 v = *(const uint4*)&cs[r * CS_STRIDE + q * 8];
        *(uint4*)(C + (size_t)(row0 + wave * 32 + r) * HID_ + col0 + q * 8) = v;
    }
}

// ---------------------------------------------------------------------------
// Per-layer projection GEMM v2: one block per graph, 8 waves (wave = head).
// ENTIRE A-tile (62x512, padded to 64 rows) staged in LDS ONCE -> exactly one
// barrier; the full K=512 MFMA stream runs with W-loads pipelined ahead
// (no barrier ever drains vmcnt). Output TRANSPOSED: hTg[b][h][d][j].
// ---------------------------------------------------------------------------
#define PB_STRIDE 516   // u16; 258 dwords == 2 mod 32 -> conflict-floor b128
__global__ __launch_bounds__(512, 4) void proj_gemm(
    const u16* __restrict__ hx, const u16* __restrict__ Wt,
    u16* __restrict__ hTg)
{
    __shared__ u16 As[64 * PB_STRIDE];   // 66,048 B -> 2 blocks/CU
    const int tid = threadIdx.x;
    const int b = blockIdx.x;            // chunk-local graph; hx pre-offset
    const int wave = tid >> 6, lane = tid & 63;
    const int lr = lane & 15, lq = lane >> 4;

    const u16* hxb = hx + (size_t)b * N_ * HID_;

    // ---- stage full A-tile (rows 62/63 zero) ----
#pragma unroll
    for (int it = 0; it < 8; it++) {
        int idx = it * 512 + tid;        // 4096 uint4 = 64 rows x 64 slots
        int row = idx >> 6, q = idx & 63;
        uint4 v = (uint4){0u, 0u, 0u, 0u};
        if (row < N_)
            v = *(const uint4*)(hxb + (size_t)row * HID_ + q * 8);
        *(uint4*)&As[row * PB_STRIDE + q * 8] = v;
    }
    __syncthreads();                     // the ONLY barrier

    f32x4 acc[4][4];
#pragma unroll
    for (int mt = 0; mt < 4; mt++)
#pragma unroll
        for (int nt = 0; nt < 4; nt++) acc[mt][nt] = (f32x4){0.f, 0.f, 0.f, 0.f};

    const u16* wp = Wt + (size_t)wave * 64 * HID_;

#pragma unroll 4
    for (int s = 0; s < 16; s++) {       // K = 16 x 32
        int k0 = s * 32 + lq * 8;
        bf16x8 af[4];
#pragma unroll
        for (int mt = 0; mt < 4; mt++)
            af[mt] = *(const bf16x8*)&As[(mt * 16 + lr) * PB_STRIDE + k0];
#pragma unroll
        for (int nt = 0; nt < 4; nt++) {
            bf16x8 bfr = *(const bf16x8*)(wp + (size_t)(nt * 16 + lr) * HID_ + k0);
#pragma unroll
            for (int mt = 0; mt < 4; mt++)
                acc[mt][nt] = __builtin_amdgcn_mfma_f32_16x16x32_bf16(
                    af[mt], bfr, acc[mt][nt], 0, 0, 0);
        }
    }

    // transposed store: hTg[((b*8+h)*64 + d)*64 + j], 8B packed (4 consec j)
    u16* outp = hTg + ((size_t)(b * 8 + wave) * 64) * 64;
#pragma unroll
    for (int nt = 0; nt < 4; nt++) {
        int d = nt * 16 + lr;
#pragma unroll
        for (int mt = 0; mt < 4; mt++) {
            ushort4 v;
            v.x = f2bf(acc[mt][nt][0]);
            v.y = f2bf(acc[mt][nt][1]);
            v.z = f2bf(acc[mt][nt][2]);
            v.w = f2bf(acc[mt][nt][3]);
            *(ushort4*)(outp + d * 64 + mt * 16 + lq * 4) = v;
        }
    }
}

// ---------------------------------------------------------------------------
// Attention: one WAVE per (graph, head); 4 units per 256-thread block,
// heads {0-3}/{4-7} of one graph per block. Zero barriers.
// ---------------------------------------------------------------------------
#define S_HT 72
#define UNIT_U16 5248   // hT 64*72 + f1/f2/c2 (3*64 f32) + msk (64 u64)
__global__ __launch_bounds__(256, 4) void attn(
    const u16* __restrict__ hTg, const uint64_t* __restrict__ masks,
    const float* __restrict__ ag, u16* __restrict__ hx)
{
    __shared__ __align__(16) u16 pool[4 * UNIT_U16];   // 42 KB
    const int tid = threadIdx.x;
    const int wu = tid >> 6, lane = tid & 63;
    const int lr = lane & 15, lq = lane >> 4;
    const int bl = blockIdx.x >> 1;
    const int head = (blockIdx.x & 1) * 4 + wu;
    const int unit = bl * 8 + head;

    u16* hT = pool + wu * UNIT_U16;
    float* f1s = (float*)(hT + 64 * S_HT);
    float* f2s = f1s + 64;
    float* c2s = f2s + 64;
    uint64_t* msk = (uint64_t*)(c2s + 64);

    const u16* src = hTg + (size_t)unit * 4096;
#pragma unroll
    for (int it = 0; it < 8; it++) {
        int idx = it * 64 + lane;
        int d = idx >> 3, q = idx & 7;
        *(uint4*)&hT[d * S_HT + q * 8] = *(const uint4*)(src + d * 64 + q * 8);
    }
    msk[lane] = (lane < N_) ? masks[(size_t)bl * 64 + lane] : 0ull;

    const float* agh = ag + head * 128;
    float p1 = 0.f, p2 = 0.f;
#pragma unroll
    for (int d = 0; d < 64; d++) {
        float hv = bf2f(hT[d * S_HT + lane]);
        p1 += hv * agh[d];
        p2 += hv * agh[64 + d];
    }
    f1s[lane] = p1;
    f2s[lane] = p2;

    {
        float m = -9e15f;
#pragma unroll 2
        for (int i = 0; i < N_; i++) {
            float z = f2s[i] + p1;
            z = fmaxf(z, 0.2f * z);
            float zm = ((msk[i] >> lane) & 1ull) ? z : -9e15f;
            m = fmaxf(m, zm);
        }
        float s = 0.f;
#pragma unroll 2
        for (int i = 0; i < N_; i++) {
            float z = f2s[i] + p1;
            z = fmaxf(z, 0.2f * z);
            float zm = ((msk[i] >> lane) & 1ull) ? z : -9e15f;
            s += __builtin_amdgcn_exp2f((zm - m) * L2E);
        }
        c2s[lane] = m * L2E + __builtin_amdgcn_logf(s);
    }

    f32x4 acc[4][4];
#pragma unroll
    for (int it = 0; it < 4; it++)
#pragma unroll
        for (int dt = 0; dt < 4; dt++) acc[it][dt] = (f32x4){0.f, 0.f, 0.f, 0.f};

#pragma unroll
    for (int kt = 0; kt < 2; kt++) {
        int j0 = kt * 32 + lq * 8;
        float4 f1a = *(const float4*)&f1s[j0];
        float4 f1b = *(const float4*)&f1s[j0 + 4];
        float4 c2a = *(const float4*)&c2s[j0];
        float4 c2b = *(const float4*)&c2s[j0 + 4];
        float f1v[8] = {f1a.x, f1a.y, f1a.z, f1a.w, f1b.x, f1b.y, f1b.z, f1b.w};
        float cv[8]  = {c2a.x, c2a.y, c2a.z, c2a.w, c2b.x, c2b.y, c2b.z, c2b.w};
        bf16x8 hb[4];
#pragma unroll
        for (int dt = 0; dt < 4; dt++)
            hb[dt] = *(const bf16x8*)&hT[(dt * 16 + lr) * S_HT + kt * 32 + lq * 8];
#pragma unroll
        for (int it = 0; it < 4; it++) {
            int i = it * 16 + lr;
            float f2i = f2s[i];
            uint64_t mi = msk[i];
            bf16x8 pf;
#pragma unroll
            for (int t = 0; t < 8; t++) {
                float z = f2i + f1v[t];
                z = fmaxf(z, 0.2f * z);
                float zm = ((mi >> (j0 + t)) & 1ull) ? z : -9e15f;
                float arg = fminf(zm * L2E - cv[t], 0.f);
                pf[t] = (__bf16)__builtin_amdgcn_exp2f(arg);
            }
#pragma unroll
            for (int dt = 0; dt < 4; dt++)
                acc[it][dt] = __builtin_amdgcn_mfma_f32_16x16x32_bf16(
                    pf, hb[dt], acc[it][dt], 0, 0, 0);
        }
    }

#pragma unroll
    for (int it = 0; it < 4; it++)
#pragma unroll
        for (int dt = 0; dt < 4; dt++)
#pragma unroll
            for (int r = 0; r < 4; r++) {
                float v = acc[it][dt][r];
                v = v > 0.f ? v : __builtin_amdgcn_exp2f(v * L2E) - 1.f;
                hT[(it * 16 + lq * 4 + r) * S_HT + dt * 16 + lr] = f2bf(v);
            }

    u16* dst = hx + ((size_t)bl * N_) * HID_ + head * FOUT_;
#pragma unroll
    for (int it = 0; it < 8; it++) {
        int idx = it * 64 + lane;
        int row = idx >> 3, q = idx & 7;
        if (row < N_)
            *(uint4*)(dst + (size_t)row * HID_ + q * 8) =
                *(const uint4*)&hT[row * S_HT + q * 8];
    }
}

// ---------------------------------------------------------------------------
// pooled[b,:] = sum_n hx[b,n,:]; logits = pooled @ W_out + b_out; log_softmax
// ---------------------------------------------------------------------------
__global__ __launch_bounds__(256) void pool_out(
    const u16* __restrict__ hx, const float* __restrict__ Wout,
    const float* __restrict__ bout, float* __restrict__ out)
{
    __shared__ float pooled[HID_];
    __shared__ float lg[3];
    const int tid = threadIdx.x;
    const int b = blockIdx.x;
    const u16* hb = hx + (size_t)b * N_ * HID_;
    for (int f = tid; f < HID_; f += 256) {
        float s = 0.f;
        for (int n = 0; n < N_; n++) s += bf2f(hb[n * HID_ + f]);
        pooled[f] = s;
    }
    __syncthreads();
    if (tid < 192) {
        int c = tid >> 6, lane = tid & 63;
        float p = 0.f;
        for (int k = lane; k < HID_; k += 64) p += pooled[k] * Wout[k * 3 + c];
        for (int off = 32; off > 0; off >>= 1) p += __shfl_down(p, off, 64);
        if (lane == 0) lg[c] = p + bout[c];
    }
    __syncthreads();
    if (tid == 0) {
        float l0 = lg[0], l1 = lg[1], l2 = lg[2];
        float m = fmaxf(l0, fmaxf(l1, l2));
        float s = __expf(l0 - m) + __expf(l1 - m) + __expf(l2 - m);
        float ls = m + logf(s);
        out[b * 3 + 0] = l0 - ls;
        out[b * 3 + 1] = l1 - ls;
        out[b * 3 + 2] = l2 - ls;
    }
}

// ---------------------------------------------------------------------------
extern "C" void kernel_launch(void* const* d_in, const int* in_sizes, int n_in,
                              void* d_out, int out_size, void* d_ws, size_t ws_size,
                              hipStream_t stream)
{
    const float* x   = (const float*)d_in[0];
    const int*   adj = (const int*)d_in[1];
    const float* bng = (const float*)d_in[2];
    const float* bnb = (const float*)d_in[3];
    const float* bnm = (const float*)d_in[4];
    const float* bnv = (const float*)d_in[5];
    const float* Wm  = (const float*)d_in[6];
    const float* bm  = (const float*)d_in[7];
    const float* Wg  = (const float*)d_in[8];
    const float* ag  = (const float*)d_in[9];
    const float* Wo  = (const float*)d_in[10];
    const float* bo  = (const float*)d_in[11];
    float* out = (float*)d_out;

    // ws layout: xb | hx | masks | wmlp_t | wgat_t | hTg (adaptive size)
    u16* xb = (u16*)d_ws;
    u16* hx = xb + (size_t)M_ * FIN_;
    uint64_t* masks = (uint64_t*)(hx + (size_t)M_ * HID_);
    u16* wmlp_t = (u16*)(masks + (size_t)B_ * 64);
    u16* wgat_t = wmlp_t + (size_t)HID_ * FIN_;
    u16* hTg = wgat_t + (size_t)LAYERS_ * HID_ * HID_;

    const size_t fixed_b = (size_t)M_ * FIN_ * 2 + (size_t)M_ * HID_ * 2
                         + (size_t)B_ * 64 * 8
                         + ((size_t)HID_ * FIN_ + (size_t)LAYERS_ * HID_ * HID_) * 2;
    size_t rem = (ws_size > fixed_b) ? ws_size - fixed_b : 0;
    int chg = 256;
    if (rem >= (size_t)2048 * 65536) chg = 2048;
    else if (rem >= (size_t)1024 * 65536) chg = 1024;
    else if (rem >= (size_t)512 * 65536) chg = 512;

    bn_cast<<<(M_ * (FIN_ / 4) + 255) / 256, 256, 0, stream>>>(x, bng, bnb, bnm, bnv, xb);

    int rep_total = HID_ * FIN_ + LAYERS_ * HID_ * HID_;
    repack_w<<<(rep_total + 255) / 256, 256, 0, stream>>>(Wm, Wg, wmlp_t, wgat_t);

    build_masks<<<B_, 256, 0, stream>>>(adj, masks);

    // MLP: hx = xb @ W_mlp + b_mlp (col-major block order, grid = 992*4)
    gemm_mfma<<<NBY_ * 4, 256, 0, stream>>>(xb, wmlp_t, bm, hx, FIN_, FIN_);

    for (int l = 0; l < LAYERS_; l++) {
        const u16* wt = wgat_t + (size_t)l * HID_ * HID_;
        const float* agl = ag + (size_t)l * HEADS_ * 2 * FOUT_;
        for (int c = 0; c < B_ / chg; c++) {
            u16* hxc = hx + (size_t)c * chg * N_ * HID_;
            const uint64_t* mc = masks + (size_t)c * chg * 64;
            proj_gemm<<<chg, 512, 0, stream>>>(hxc, wt, hTg);
            attn<<<chg * 2, 256, 0, stream>>>(hTg, mc, agl, hxc);
        }
    }
    pool_out<<<B_, 256, 0, stream>>>(hx, Wo, bo, out);
}